// Round 2
// baseline (373.288 us; speedup 1.0000x reference)
//
#include <hip/hip_runtime.h>
#include <hip/hip_bf16.h>
#include <type_traits>

// SelfAttention fused block, MI355X/gfx950.
// I/O is fp32 (per reference dtypes); internal compute bf16 with fp32 accum.
// Pipeline: LN(keys), LN(values) -> qk GEMM -> LN(q), LN(k) -> v GEMM ->
//           flash attention (per (b,h), 64-row q tiles) -> out GEMM + bias.
// GEMMs: 128x128 tile, BK=32, mfma_f32_16x16x32_bf16, global_load_lds(16B).

typedef __hip_bfloat16 bf16;
typedef __attribute__((ext_vector_type(8))) short bf16x8;
typedef __attribute__((ext_vector_type(4))) float f32x4;

#define MFMA_BF16(a, b, c) __builtin_amdgcn_mfma_f32_16x16x32_bf16((a), (b), (c), 0, 0, 0)

__device__ __forceinline__ float us2f(unsigned short u) {
  unsigned int v = ((unsigned int)u) << 16;
  return __builtin_bit_cast(float, v);
}

// async global->LDS, 16B per lane; lane i's dest = wave-uniform base + i*16
__device__ __forceinline__ void gl_lds16(const bf16* g, bf16* l) {
  __builtin_amdgcn_global_load_lds(
      (const __attribute__((address_space(1))) void*)g,
      (__attribute__((address_space(3))) void*)l, 16, 0, 0);
}

// ---------------- LayerNorm: one block per row, D==1024, 256 threads ----------------
// TIN = float (raw inputs) or bf16 (qk intermediate). Output bf16.
template <typename TIN>
__global__ __launch_bounds__(256) void ln_kernel(
    const TIN* __restrict__ in, int stride,
    const float* __restrict__ gamma, const float* __restrict__ beta,
    bf16* __restrict__ out, int D)
{
  const int row = blockIdx.x;
  const int t = threadIdx.x;
  float x0, x1, x2, x3;
  if constexpr (std::is_same_v<TIN, float>) {
    float4 u = *(const float4*)(in + (size_t)row * stride + t * 4);
    x0 = u.x; x1 = u.y; x2 = u.z; x3 = u.w;
  } else {
    ushort4 u = *(const ushort4*)(in + (size_t)row * stride + t * 4);
    x0 = us2f(u.x); x1 = us2f(u.y); x2 = us2f(u.z); x3 = us2f(u.w);
  }
  float s = x0 + x1 + x2 + x3;
  float s2 = x0 * x0 + x1 * x1 + x2 * x2 + x3 * x3;
#pragma unroll
  for (int m = 1; m < 64; m <<= 1) {
    s += __shfl_xor(s, m);
    s2 += __shfl_xor(s2, m);
  }
  __shared__ float red[10];
  const int w = t >> 6, lane = t & 63;
  if (lane == 0) { red[w] = s; red[4 + w] = s2; }
  __syncthreads();
  if (t == 0) {
    float S = red[0] + red[1] + red[2] + red[3];
    float S2 = red[4] + red[5] + red[6] + red[7];
    float mu = S / (float)D;
    float var = S2 / (float)D - mu * mu;
    red[8] = mu;
    red[9] = rsqrtf(var + 1e-5f);
  }
  __syncthreads();
  const float mu = red[8], rs = red[9];
  float4 g4 = *(const float4*)(gamma + t * 4);
  float4 b4 = *(const float4*)(beta + t * 4);
  __align__(8) bf16 o[4];
  o[0] = __float2bfloat16((x0 - mu) * rs * g4.x + b4.x);
  o[1] = __float2bfloat16((x1 - mu) * rs * g4.y + b4.y);
  o[2] = __float2bfloat16((x2 - mu) * rs * g4.z + b4.z);
  o[3] = __float2bfloat16((x3 - mu) * rs * g4.w + b4.w);
  *(ushort4*)(out + (size_t)row * D + t * 4) = *(const ushort4*)o;
}

// ---------------- transpose: in (R,C) TIN -> out (C,R) bf16, 64x64 tiles, batched by z ----------------
template <typename TIN>
__global__ __launch_bounds__(256) void transpose_kernel(
    const TIN* __restrict__ in, bf16* __restrict__ out, int R, int C)
{
  __shared__ float tile[64][68];  // pad 68: 2-way bank alias only (free on gfx950)
  const size_t boff = (size_t)blockIdx.z * (size_t)R * (size_t)C;
  const int r0 = blockIdx.y * 64, c0 = blockIdx.x * 64;
  const int t = threadIdx.x;
  const int lr = t >> 2, lc = (t & 3) * 16;
  if constexpr (std::is_same_v<TIN, float>) {
    const float* src = in + boff + (size_t)(r0 + lr) * C + (c0 + lc);
#pragma unroll
    for (int i = 0; i < 4; ++i) {
      float4 u = *(const float4*)(src + i * 4);
      tile[lr][lc + i * 4 + 0] = u.x;
      tile[lr][lc + i * 4 + 1] = u.y;
      tile[lr][lc + i * 4 + 2] = u.z;
      tile[lr][lc + i * 4 + 3] = u.w;
    }
  } else {
    const bf16* src = in + boff + (size_t)(r0 + lr) * C + (c0 + lc);
#pragma unroll
    for (int i = 0; i < 2; ++i) {
      ushort4 a = *(const ushort4*)(src + i * 8);
      ushort4 b = *(const ushort4*)(src + i * 8 + 4);
      tile[lr][lc + i * 8 + 0] = us2f(a.x); tile[lr][lc + i * 8 + 1] = us2f(a.y);
      tile[lr][lc + i * 8 + 2] = us2f(a.z); tile[lr][lc + i * 8 + 3] = us2f(a.w);
      tile[lr][lc + i * 8 + 4] = us2f(b.x); tile[lr][lc + i * 8 + 5] = us2f(b.y);
      tile[lr][lc + i * 8 + 6] = us2f(b.z); tile[lr][lc + i * 8 + 7] = us2f(b.w);
    }
  }
  __syncthreads();
  __align__(16) bf16 tmp[16];
#pragma unroll
  for (int j = 0; j < 16; ++j) tmp[j] = __float2bfloat16(tile[lc + j][lr]);
  bf16* dst = out + boff + (size_t)(c0 + lr) * R + (r0 + lc);
  *(bf16x8*)dst       = *(const bf16x8*)&tmp[0];
  *(bf16x8*)(dst + 8) = *(const bf16x8*)&tmp[8];
}

// ---------------- GEMM: C(M,N) = A(M,K) @ Bt(N,K)^T (+bias), bf16 in, fp32 accum ----------------
// TOUT = bf16 (intermediates) or float (final output). bias is fp32.
// grid = (N/128, M/128), 256 threads (4 waves, 2x2, each 64x64 = 4x4 mfma tiles)
template <typename TOUT>
__global__ __launch_bounds__(256) void gemm_bt_kernel(
    const bf16* __restrict__ A, const bf16* __restrict__ Bt,
    const float* __restrict__ bias, TOUT* __restrict__ C,
    int M, int N, int K, int has_bias)
{
  __shared__ __align__(16) bf16 lA[128 * 32];
  __shared__ __align__(16) bf16 lB[128 * 32];
  const int t = threadIdx.x;
  const int w = t >> 6, lane = t & 63, l15 = lane & 15, quad = lane >> 4;
  const int wy = w >> 1, wx = w & 1;
  const int by = blockIdx.y, bx = blockIdx.x;
  const bf16* Ab = A + (size_t)by * 128 * K;
  const bf16* Bb = Bt + (size_t)bx * 128 * K;
  f32x4 acc[4][4] = {};

  for (int kc = 0; kc < K; kc += 32) {
    __syncthreads();  // prior iter's frag reads done before overwrite
#pragma unroll
    for (int i = 0; i < 2; ++i) {
      int s = i * 256 + t;
      gl_lds16(Ab + (size_t)(s >> 2) * K + kc + (s & 3) * 8, lA + s * 8);
      gl_lds16(Bb + (size_t)(s >> 2) * K + kc + (s & 3) * 8, lB + s * 8);
    }
    __syncthreads();  // drains vmcnt: staged data visible
    bf16x8 af[4], bfr[4];
#pragma unroll
    for (int mt = 0; mt < 4; ++mt)
      af[mt] = *(const bf16x8*)&lA[(wy * 64 + mt * 16 + l15) * 32 + quad * 8];
#pragma unroll
    for (int nt = 0; nt < 4; ++nt)
      bfr[nt] = *(const bf16x8*)&lB[(wx * 64 + nt * 16 + l15) * 32 + quad * 8];
#pragma unroll
    for (int mt = 0; mt < 4; ++mt)
#pragma unroll
      for (int nt = 0; nt < 4; ++nt)
        acc[mt][nt] = MFMA_BF16(af[mt], bfr[nt], acc[mt][nt]);
  }

  const int row_base = by * 128 + wy * 64;
  const int col_base = bx * 128 + wx * 64;
#pragma unroll
  for (int mt = 0; mt < 4; ++mt)
#pragma unroll
    for (int nt = 0; nt < 4; ++nt) {
      const int col = col_base + nt * 16 + l15;
      const float bb = has_bias ? bias[col] : 0.0f;
#pragma unroll
      for (int r = 0; r < 4; ++r) {
        const int row = row_base + mt * 16 + quad * 4 + r;
        float v = acc[mt][nt][r] + bb;
        if constexpr (std::is_same_v<TOUT, bf16>)
          C[(size_t)row * N + col] = __float2bfloat16(v);
        else
          C[(size_t)row * N + col] = v;
      }
    }
}

// ---------------- Flash attention ----------------
// q,k: (B*N, ID) row-major (head h at cols h*64..h*64+63), vt: per (b,h) V^T (64 d x 2048 n)
// grid = (N/64, B*H), 256 threads; each wave owns 16 q rows.
__global__ __launch_bounds__(256) void flash_kernel(
    const bf16* __restrict__ Q, const bf16* __restrict__ Km,
    const bf16* __restrict__ Vt, bf16* __restrict__ O)
{
  __shared__ __align__(16) bf16 lQ[64 * 64];
  __shared__ __align__(16) bf16 lK[64 * 64];
  __shared__ __align__(16) bf16 lV[64 * 64];
  __shared__ __align__(16) bf16 lP[64 * 64];
  const float SCALE = 0.03125f;  // ID^-0.5 = 1/32
  const int t = threadIdx.x;
  const int w = t >> 6, lane = t & 63, l15 = lane & 15, quad = lane >> 4;
  const int qt = blockIdx.x, bh = blockIdx.y;
  const int b = bh >> 4, h = bh & 15;
  const bf16* qbase = Q + ((size_t)(b * 2048 + qt * 64)) * 1024 + h * 64;
  const bf16* kbase = Km + ((size_t)(b * 2048)) * 1024 + h * 64;
  const bf16* vbase = Vt + ((size_t)(b * 1024 + h * 64)) * 2048;

  // stage Q tile (64 rows x 64 cols, 128B/row = 8 slots of 16B)
#pragma unroll
  for (int i = 0; i < 2; ++i) {
    int s = i * 256 + t;
    gl_lds16(qbase + (size_t)(s >> 3) * 1024 + (s & 7) * 8, lQ + s * 8);
  }
  __syncthreads();
  const bf16x8 aq0 = *(const bf16x8*)&lQ[(w * 16 + l15) * 64 + quad * 8];
  const bf16x8 aq1 = *(const bf16x8*)&lQ[(w * 16 + l15) * 64 + 32 + quad * 8];

  float m_r[4], l_r[4];
  f32x4 o_acc[4] = {};
#pragma unroll
  for (int r = 0; r < 4; ++r) { m_r[r] = -1e30f; l_r[r] = 0.0f; }

  for (int kt = 0; kt < 32; ++kt) {
    __syncthreads();  // prior iter's lK/lV/lP reads done
#pragma unroll
    for (int i = 0; i < 2; ++i) {
      int s = i * 256 + t;
      gl_lds16(kbase + (size_t)(kt * 64 + (s >> 3)) * 1024 + (s & 7) * 8, lK + s * 8);
      gl_lds16(vbase + (size_t)(s >> 3) * 2048 + kt * 64 + (s & 7) * 8, lV + s * 8);
    }
    __syncthreads();

    // S = Q K^T for this wave's 16 q rows x 64 k cols
    f32x4 sfr[4];
#pragma unroll
    for (int nt = 0; nt < 4; ++nt) {
      bf16x8 bk0 = *(const bf16x8*)&lK[(nt * 16 + l15) * 64 + quad * 8];
      bf16x8 bk1 = *(const bf16x8*)&lK[(nt * 16 + l15) * 64 + 32 + quad * 8];
      f32x4 z = {};
      z = MFMA_BF16(aq0, bk0, z);
      z = MFMA_BF16(aq1, bk1, z);
      sfr[nt] = z * SCALE;
    }

    // online softmax: row (quad*4+r) stats via xor-shuffle across the 16-lane group
    float alpha[4];
#pragma unroll
    for (int r = 0; r < 4; ++r) {
      float vmax = fmaxf(fmaxf(sfr[0][r], sfr[1][r]), fmaxf(sfr[2][r], sfr[3][r]));
#pragma unroll
      for (int m = 1; m < 16; m <<= 1) vmax = fmaxf(vmax, __shfl_xor(vmax, m));
      float mnew = fmaxf(m_r[r], vmax);
      alpha[r] = __expf(m_r[r] - mnew);
      float ps = 0.0f;
#pragma unroll
      for (int nt = 0; nt < 4; ++nt) {
        float p = __expf(sfr[nt][r] - mnew);
        sfr[nt][r] = p;
        ps += p;
      }
#pragma unroll
      for (int m = 1; m < 16; m <<= 1) ps += __shfl_xor(ps, m);
      l_r[r] = l_r[r] * alpha[r] + ps;
      m_r[r] = mnew;
    }

    // P: C-layout -> LDS -> A-layout (each wave owns its 16x64 strip)
#pragma unroll
    for (int nt = 0; nt < 4; ++nt)
#pragma unroll
      for (int r = 0; r < 4; ++r)
        lP[(w * 16 + quad * 4 + r) * 64 + nt * 16 + l15] = __float2bfloat16(sfr[nt][r]);
    __syncthreads();

#pragma unroll
    for (int dt = 0; dt < 4; ++dt)
#pragma unroll
      for (int r = 0; r < 4; ++r) o_acc[dt][r] *= alpha[r];

    const bf16x8 ap0 = *(const bf16x8*)&lP[(w * 16 + l15) * 64 + quad * 8];
    const bf16x8 ap1 = *(const bf16x8*)&lP[(w * 16 + l15) * 64 + 32 + quad * 8];
#pragma unroll
    for (int dt = 0; dt < 4; ++dt) {
      bf16x8 bv0 = *(const bf16x8*)&lV[(dt * 16 + l15) * 64 + quad * 8];
      bf16x8 bv1 = *(const bf16x8*)&lV[(dt * 16 + l15) * 64 + 32 + quad * 8];
      o_acc[dt] = MFMA_BF16(ap0, bv0, o_acc[dt]);
      o_acc[dt] = MFMA_BF16(ap1, bv1, o_acc[dt]);
    }
  }

#pragma unroll
  for (int r = 0; r < 4; ++r) {
    const float inv = 1.0f / l_r[r];
    const int row = b * 2048 + qt * 64 + w * 16 + quad * 4 + r;
#pragma unroll
    for (int dt = 0; dt < 4; ++dt) {
      const int col = h * 64 + dt * 16 + l15;
      O[(size_t)row * 1024 + col] = __float2bfloat16(o_acc[dt][r] * inv);
    }
  }
}

extern "C" void kernel_launch(void* const* d_in, const int* in_sizes, int n_in,
                              void* d_out, int out_size, void* d_ws, size_t ws_size,
                              hipStream_t stream)
{
  (void)in_sizes; (void)n_in; (void)out_size; (void)ws_size;
  const float* keys   = (const float*)d_in[0];
  const float* values = (const float*)d_in[1];
  const float* qk_g   = (const float*)d_in[2];
  const float* qk_b   = (const float*)d_in[3];
  const float* val_g  = (const float*)d_in[4];
  const float* val_b  = (const float*)d_in[5];
  const float* key_g  = (const float*)d_in[6];
  const float* key_b  = (const float*)d_in[7];
  const float* qry_g  = (const float*)d_in[8];
  const float* qry_b  = (const float*)d_in[9];
  const float* w_qk   = (const float*)d_in[10];
  const float* w_v    = (const float*)d_in[11];
  const float* w_out  = (const float*)d_in[12];
  const float* b_out  = (const float*)d_in[13];
  float* out = (float*)d_out;

  char* ws = (char*)d_ws;
  const size_t MB = 1024 * 1024;
  // bf16 intermediates; lifetimes allow aliasing: total 56 MB
  bf16* keys_ln   = (bf16*)(ws + 0);        // 8MB  [L1..L6]
  bf16* v         = (bf16*)(ws + 0);        // 8MB  [L9..L10] (keys_ln dead)
  bf16* values_ln = (bf16*)(ws + 8 * MB);   // 8MB  [L2..L9]
  bf16* qk        = (bf16*)(ws + 16 * MB);  // 16MB [L6..L8]
  bf16* attn      = (bf16*)(ws + 16 * MB);  // 8MB  [L11..L12] (qk dead)
  bf16* vt        = (bf16*)(ws + 24 * MB);  // 8MB  [L10..L11]
  bf16* qln       = (bf16*)(ws + 32 * MB);  // 8MB  [L7..L11]
  bf16* kln       = (bf16*)(ws + 40 * MB);  // 8MB  [L8..L11]
  bf16* wqkT      = (bf16*)(ws + 48 * MB);  // 4MB  [L3..L6]
  bf16* wvT       = (bf16*)(ws + 52 * MB);  // 2MB  [L4..L9]
  bf16* woutT     = (bf16*)(ws + 54 * MB);  // 2MB  [L5..L12]

  // L1/L2: input layernorms (fp32 in -> bf16 out)
  ln_kernel<float><<<dim3(4096), 256, 0, stream>>>(keys, 1024, qk_g, qk_b, keys_ln, 1024);
  ln_kernel<float><<<dim3(4096), 256, 0, stream>>>(values, 1024, val_g, val_b, values_ln, 1024);
  // L3-L5: weight transposes (fp32 in -> bf16 (N,K) layouts)
  transpose_kernel<float><<<dim3(32, 16, 1), 256, 0, stream>>>(w_qk, wqkT, 1024, 2048);
  transpose_kernel<float><<<dim3(16, 16, 1), 256, 0, stream>>>(w_v, wvT, 1024, 1024);
  transpose_kernel<float><<<dim3(16, 16, 1), 256, 0, stream>>>(w_out, woutT, 1024, 1024);
  // L6: qk = keys_ln @ w_qk   (4096 x 2048)
  gemm_bt_kernel<bf16><<<dim3(16, 32), 256, 0, stream>>>(keys_ln, wqkT, nullptr, qk, 4096, 2048, 1024, 0);
  // L7/L8: q/k layernorms (bf16 in, row stride 2048, halves of qk)
  ln_kernel<bf16><<<dim3(4096), 256, 0, stream>>>(qk, 2048, qry_g, qry_b, qln, 1024);
  ln_kernel<bf16><<<dim3(4096), 256, 0, stream>>>(qk + 1024, 2048, key_g, key_b, kln, 1024);
  // L9: v = values_ln @ w_v   (4096 x 1024)
  gemm_bt_kernel<bf16><<<dim3(8, 32), 256, 0, stream>>>(values_ln, wvT, nullptr, v, 4096, 1024, 1024, 0);
  // L10: per-batch transpose v -> vt[(b*1024 + c)*2048 + n]
  transpose_kernel<bf16><<<dim3(16, 32, 2), 256, 0, stream>>>(v, vt, 2048, 1024);
  // L11: flash attention -> attn (B*N, ID) with heads re-interleaved
  flash_kernel<<<dim3(32, 32), 256, 0, stream>>>(qln, kln, vt, attn);
  // L12: out = attn @ w_out + b_out  (fp32 output)
  gemm_bt_kernel<float><<<dim3(8, 32), 256, 0, stream>>>(attn, woutT, b_out, out, 4096, 1024, 1024, 1);
}

// Round 3
// 289.165 us; speedup vs baseline: 1.2909x; 1.2909x over previous
//
#include <hip/hip_runtime.h>
#include <hip/hip_bf16.h>
#include <type_traits>

// SelfAttention fused block, MI355X/gfx950.
// I/O fp32; internal bf16 with fp32 accum.
// R3: flash rewritten — S^T orientation, no-max softmax (LN-bounded scores),
//     XOR-swizzled LDS (conflict-free b128 frag reads), M=32 rows/wave,
//     P via 4x ds_write_b64 + 2x ds_read_b128 per m-set.

typedef __hip_bfloat16 bf16;
typedef __attribute__((ext_vector_type(8))) short bf16x8;
typedef __attribute__((ext_vector_type(4))) float f32x4;

#define MFMA_BF16(a, b, c) __builtin_amdgcn_mfma_f32_16x16x32_bf16((a), (b), (c), 0, 0, 0)

__device__ __forceinline__ float us2f(unsigned short u) {
  unsigned int v = ((unsigned int)u) << 16;
  return __builtin_bit_cast(float, v);
}

// async global->LDS, 16B per lane; lane i's dest = wave-uniform base + i*16
__device__ __forceinline__ void gl_lds16(const bf16* g, bf16* l) {
  __builtin_amdgcn_global_load_lds(
      (const __attribute__((address_space(1))) void*)g,
      (__attribute__((address_space(3))) void*)l, 16, 0, 0);
}

// ---------------- LayerNorm: one block per row, D==1024, 256 threads ----------------
template <typename TIN>
__global__ __launch_bounds__(256) void ln_kernel(
    const TIN* __restrict__ in, int stride,
    const float* __restrict__ gamma, const float* __restrict__ beta,
    bf16* __restrict__ out, int D)
{
  const int row = blockIdx.x;
  const int t = threadIdx.x;
  float x0, x1, x2, x3;
  if constexpr (std::is_same_v<TIN, float>) {
    float4 u = *(const float4*)(in + (size_t)row * stride + t * 4);
    x0 = u.x; x1 = u.y; x2 = u.z; x3 = u.w;
  } else {
    ushort4 u = *(const ushort4*)(in + (size_t)row * stride + t * 4);
    x0 = us2f(u.x); x1 = us2f(u.y); x2 = us2f(u.z); x3 = us2f(u.w);
  }
  float s = x0 + x1 + x2 + x3;
  float s2 = x0 * x0 + x1 * x1 + x2 * x2 + x3 * x3;
#pragma unroll
  for (int m = 1; m < 64; m <<= 1) {
    s += __shfl_xor(s, m);
    s2 += __shfl_xor(s2, m);
  }
  __shared__ float red[10];
  const int w = t >> 6, lane = t & 63;
  if (lane == 0) { red[w] = s; red[4 + w] = s2; }
  __syncthreads();
  if (t == 0) {
    float S = red[0] + red[1] + red[2] + red[3];
    float S2 = red[4] + red[5] + red[6] + red[7];
    float mu = S / (float)D;
    float var = S2 / (float)D - mu * mu;
    red[8] = mu;
    red[9] = rsqrtf(var + 1e-5f);
  }
  __syncthreads();
  const float mu = red[8], rs = red[9];
  float4 g4 = *(const float4*)(gamma + t * 4);
  float4 b4 = *(const float4*)(beta + t * 4);
  __align__(8) bf16 o[4];
  o[0] = __float2bfloat16((x0 - mu) * rs * g4.x + b4.x);
  o[1] = __float2bfloat16((x1 - mu) * rs * g4.y + b4.y);
  o[2] = __float2bfloat16((x2 - mu) * rs * g4.z + b4.z);
  o[3] = __float2bfloat16((x3 - mu) * rs * g4.w + b4.w);
  *(ushort4*)(out + (size_t)row * D + t * 4) = *(const ushort4*)o;
}

// ---------------- transpose: in (R,C) TIN -> out (C,R) bf16, 64x64 tiles, batched by z ----------------
template <typename TIN>
__global__ __launch_bounds__(256) void transpose_kernel(
    const TIN* __restrict__ in, bf16* __restrict__ out, int R, int C)
{
  __shared__ float tile[64][68];
  const size_t boff = (size_t)blockIdx.z * (size_t)R * (size_t)C;
  const int r0 = blockIdx.y * 64, c0 = blockIdx.x * 64;
  const int t = threadIdx.x;
  const int lr = t >> 2, lc = (t & 3) * 16;
  if constexpr (std::is_same_v<TIN, float>) {
    const float* src = in + boff + (size_t)(r0 + lr) * C + (c0 + lc);
#pragma unroll
    for (int i = 0; i < 4; ++i) {
      float4 u = *(const float4*)(src + i * 4);
      tile[lr][lc + i * 4 + 0] = u.x;
      tile[lr][lc + i * 4 + 1] = u.y;
      tile[lr][lc + i * 4 + 2] = u.z;
      tile[lr][lc + i * 4 + 3] = u.w;
    }
  } else {
    const bf16* src = in + boff + (size_t)(r0 + lr) * C + (c0 + lc);
#pragma unroll
    for (int i = 0; i < 2; ++i) {
      ushort4 a = *(const ushort4*)(src + i * 8);
      ushort4 b = *(const ushort4*)(src + i * 8 + 4);
      tile[lr][lc + i * 8 + 0] = us2f(a.x); tile[lr][lc + i * 8 + 1] = us2f(a.y);
      tile[lr][lc + i * 8 + 2] = us2f(a.z); tile[lr][lc + i * 8 + 3] = us2f(a.w);
      tile[lr][lc + i * 8 + 4] = us2f(b.x); tile[lr][lc + i * 8 + 5] = us2f(b.y);
      tile[lr][lc + i * 8 + 6] = us2f(b.z); tile[lr][lc + i * 8 + 7] = us2f(b.w);
    }
  }
  __syncthreads();
  __align__(16) bf16 tmp[16];
#pragma unroll
  for (int j = 0; j < 16; ++j) tmp[j] = __float2bfloat16(tile[lc + j][lr]);
  bf16* dst = out + boff + (size_t)(c0 + lr) * R + (r0 + lc);
  *(bf16x8*)dst       = *(const bf16x8*)&tmp[0];
  *(bf16x8*)(dst + 8) = *(const bf16x8*)&tmp[8];
}

// ---------------- GEMM: C(M,N) = A(M,K) @ Bt(N,K)^T (+bias), bf16 in, fp32 accum ----------------
template <typename TOUT>
__global__ __launch_bounds__(256) void gemm_bt_kernel(
    const bf16* __restrict__ A, const bf16* __restrict__ Bt,
    const float* __restrict__ bias, TOUT* __restrict__ C,
    int M, int N, int K, int has_bias)
{
  __shared__ __align__(16) bf16 lA[128 * 32];
  __shared__ __align__(16) bf16 lB[128 * 32];
  const int t = threadIdx.x;
  const int w = t >> 6, lane = t & 63, l15 = lane & 15, quad = lane >> 4;
  const int wy = w >> 1, wx = w & 1;
  const int by = blockIdx.y, bx = blockIdx.x;
  const bf16* Ab = A + (size_t)by * 128 * K;
  const bf16* Bb = Bt + (size_t)bx * 128 * K;
  f32x4 acc[4][4] = {};

  for (int kc = 0; kc < K; kc += 32) {
    __syncthreads();
#pragma unroll
    for (int i = 0; i < 2; ++i) {
      int s = i * 256 + t;
      gl_lds16(Ab + (size_t)(s >> 2) * K + kc + (s & 3) * 8, lA + s * 8);
      gl_lds16(Bb + (size_t)(s >> 2) * K + kc + (s & 3) * 8, lB + s * 8);
    }
    __syncthreads();
    bf16x8 af[4], bfr[4];
#pragma unroll
    for (int mt = 0; mt < 4; ++mt)
      af[mt] = *(const bf16x8*)&lA[(wy * 64 + mt * 16 + l15) * 32 + quad * 8];
#pragma unroll
    for (int nt = 0; nt < 4; ++nt)
      bfr[nt] = *(const bf16x8*)&lB[(wx * 64 + nt * 16 + l15) * 32 + quad * 8];
#pragma unroll
    for (int mt = 0; mt < 4; ++mt)
#pragma unroll
      for (int nt = 0; nt < 4; ++nt)
        acc[mt][nt] = MFMA_BF16(af[mt], bfr[nt], acc[mt][nt]);
  }

  const int row_base = by * 128 + wy * 64;
  const int col_base = bx * 128 + wx * 64;
#pragma unroll
  for (int mt = 0; mt < 4; ++mt)
#pragma unroll
    for (int nt = 0; nt < 4; ++nt) {
      const int col = col_base + nt * 16 + l15;
      const float bb = has_bias ? bias[col] : 0.0f;
#pragma unroll
      for (int r = 0; r < 4; ++r) {
        const int row = row_base + mt * 16 + quad * 4 + r;
        float v = acc[mt][nt][r] + bb;
        if constexpr (std::is_same_v<TOUT, bf16>)
          C[(size_t)row * N + col] = __float2bfloat16(v);
        else
          C[(size_t)row * N + col] = v;
      }
    }
}

// ---------------- Flash attention (R3) ----------------
// Q/K: (B*N, 1024) rows, head h at cols h*64..h*64+63. Vt: per (b,h) V^T (64 d x 2048 n).
// Block: 128 q rows (4 waves x 32), loop over 32 k-tiles of 64.
// S^T = MFMA(a=K-frag, b=Q-frag) -> C[n][m] (m = l15, n = quad*4+r): softmax rows
// in-lane; no max-subtraction (LN bounds |s| <= 32). P -> LDS (b64 writes, m-major,
// stride 72) -> B-frags for PV: O^T[d][m] = MFMA(a=Vt-frag, b=P-frag).
// XOR swizzle c_lds = c ^ (row&7) on lQ/lK/lV for conflict-free b128 frag reads.
__global__ __launch_bounds__(256) void flash_kernel(
    const bf16* __restrict__ Q, const bf16* __restrict__ Km,
    const bf16* __restrict__ Vt, bf16* __restrict__ O)
{
  // lPQ: per-wave P region 32 rows x 72 (9216 elems total); also Q staging (8192) at start.
  // lK, lV: 64 x 64 each.
  __shared__ __align__(16) bf16 smem[9216 + 4096 + 4096];
  bf16* lPQ = smem;
  bf16* lK = smem + 9216;
  bf16* lV = smem + 9216 + 4096;
  const float SCALE = 0.03125f;  // 1/32
  const int t = threadIdx.x;
  const int w = t >> 6, lane = t & 63, l15 = lane & 15, quad = lane >> 4;
  const int qt = blockIdx.x, bh = blockIdx.y;
  const int b = bh >> 4, h = bh & 15;
  const int qrow0 = b * 2048 + qt * 128;
  const bf16* qbase = Q + (size_t)qrow0 * 1024 + h * 64;
  const bf16* kbase = Km + ((size_t)(b * 2048)) * 1024 + h * 64;
  const bf16* vbase = Vt + ((size_t)(b * 1024 + h * 64)) * 2048;
  bf16* lPm = lPQ + w * (32 * 72);

  // ---- stage Q (128 rows x 64), swizzled: lds chunk c holds global chunk c^(row&7)
#pragma unroll
  for (int i = 0; i < 4; ++i) {
    int s = i * 256 + t;
    int row = s >> 3, c = s & 7;
    gl_lds16(qbase + (size_t)row * 1024 + ((c ^ (row & 7)) << 3), lPQ + s * 8);
  }
  __syncthreads();
  // Q frags (B-operand): B[m = mset*16+l15][k = quad*8+j]; row&7 == l15&7
  bf16x8 qf[2][2];
  {
    const int sw = (quad ^ (l15 & 7)) << 3;
#pragma unroll
    for (int mset = 0; mset < 2; ++mset) {
      const int row = w * 32 + mset * 16 + l15;
      qf[mset][0] = *(const bf16x8*)&lPQ[row * 64 + sw];
      qf[mset][1] = *(const bf16x8*)&lPQ[row * 64 + (sw ^ 32)];
    }
  }

  f32x4 o_acc[4][2] = {};   // [dt][mset] -> O^T tile: row d = dt*16+quad*4+r, col m = mset*16+l15
  f32x4 l_vec[2] = {};      // in-lane partial row sums (row m = l15 per mset)

  for (int kt = 0; kt < 32; ++kt) {
    __syncthreads();  // prior iter frag reads + Q reads (iter 0) done before overwrite
#pragma unroll
    for (int i = 0; i < 2; ++i) {
      int s = i * 256 + t;
      int row = s >> 3, c = (s & 7) ^ (row & 7);
      gl_lds16(kbase + (size_t)(kt * 64 + row) * 1024 + (c << 3), lK + s * 8);
      gl_lds16(vbase + (size_t)row * 2048 + kt * 64 + (c << 3), lV + s * 8);
    }
    __syncthreads();  // vmcnt drained: staged data visible

    const int sw = (quad ^ (l15 & 7)) << 3;
    // K frags (A-operand): A[n = nt*16+l15][k-chunk], reused for both msets
    bf16x8 kf[4][2];
#pragma unroll
    for (int nt = 0; nt < 4; ++nt) {
      kf[nt][0] = *(const bf16x8*)&lK[(nt * 16 + l15) * 64 + sw];
      kf[nt][1] = *(const bf16x8*)&lK[(nt * 16 + l15) * 64 + (sw ^ 32)];
    }
    // V frags (A-operand): A[d = dt*16+l15][n-chunk]
    bf16x8 vf[4][2];
#pragma unroll
    for (int dt = 0; dt < 4; ++dt) {
      vf[dt][0] = *(const bf16x8*)&lV[(dt * 16 + l15) * 64 + sw];
      vf[dt][1] = *(const bf16x8*)&lV[(dt * 16 + l15) * 64 + (sw ^ 32)];
    }

    // S^T + exp + P write (both msets), then one barrier, then PV
#pragma unroll
    for (int mset = 0; mset < 2; ++mset) {
#pragma unroll
      for (int nt = 0; nt < 4; ++nt) {
        f32x4 z = {};
        z = MFMA_BF16(kf[nt][0], qf[mset][0], z);
        z = MFMA_BF16(kf[nt][1], qf[mset][1], z);
        f32x4 p;
#pragma unroll
        for (int r = 0; r < 4; ++r) p[r] = __expf(z[r] * SCALE);
        l_vec[mset] += p;
        __align__(8) bf16 pb[4];
#pragma unroll
        for (int r = 0; r < 4; ++r) pb[r] = __float2bfloat16(p[r]);
        // P[m = mset*16+l15][n = nt*16+quad*4 + r]: 4 contiguous n -> b64
        *(uint2*)&lPm[(mset * 16 + l15) * 72 + nt * 16 + quad * 4] = *(const uint2*)pb;
      }
    }
    __syncthreads();  // P visible (also orders vs other waves' lPm? regions disjoint; barrier for lgkm anyway)

#pragma unroll
    for (int mset = 0; mset < 2; ++mset) {
      // P B-frags: B[m = mset*16+l15][n = quad*8+j (+32)]
      const bf16* pr = &lPm[(mset * 16 + l15) * 72 + quad * 8];
      bf16x8 pf0 = *(const bf16x8*)pr;
      bf16x8 pf1 = *(const bf16x8*)(pr + 32);
#pragma unroll
      for (int dt = 0; dt < 4; ++dt) {
        o_acc[dt][mset] = MFMA_BF16(vf[dt][0], pf0, o_acc[dt][mset]);
        o_acc[dt][mset] = MFMA_BF16(vf[dt][1], pf1, o_acc[dt][mset]);
      }
    }
  }

  // ---- epilogue: row sums (cross-quad) + divide + store O^T fragments
#pragma unroll
  for (int mset = 0; mset < 2; ++mset) {
    float tsum = l_vec[mset][0] + l_vec[mset][1] + l_vec[mset][2] + l_vec[mset][3];
    tsum += __shfl_xor(tsum, 16);
    tsum += __shfl_xor(tsum, 32);
    const float inv = 1.0f / tsum;
    const int m = qrow0 + w * 32 + mset * 16 + l15;
#pragma unroll
    for (int dt = 0; dt < 4; ++dt) {
      __align__(8) bf16 ob[4];
#pragma unroll
      for (int r = 0; r < 4; ++r) ob[r] = __float2bfloat16(o_acc[dt][mset][r] * inv);
      *(uint2*)&O[(size_t)m * 1024 + h * 64 + dt * 16 + quad * 4] = *(const uint2*)ob;
    }
  }
}

extern "C" void kernel_launch(void* const* d_in, const int* in_sizes, int n_in,
                              void* d_out, int out_size, void* d_ws, size_t ws_size,
                              hipStream_t stream)
{
  (void)in_sizes; (void)n_in; (void)out_size; (void)ws_size;
  const float* keys   = (const float*)d_in[0];
  const float* values = (const float*)d_in[1];
  const float* qk_g   = (const float*)d_in[2];
  const float* qk_b   = (const float*)d_in[3];
  const float* val_g  = (const float*)d_in[4];
  const float* val_b  = (const float*)d_in[5];
  const float* key_g  = (const float*)d_in[6];
  const float* key_b  = (const float*)d_in[7];
  const float* qry_g  = (const float*)d_in[8];
  const float* qry_b  = (const float*)d_in[9];
  const float* w_qk   = (const float*)d_in[10];
  const float* w_v    = (const float*)d_in[11];
  const float* w_out  = (const float*)d_in[12];
  const float* b_out  = (const float*)d_in[13];
  float* out = (float*)d_out;

  char* ws = (char*)d_ws;
  const size_t MB = 1024 * 1024;
  bf16* keys_ln   = (bf16*)(ws + 0);        // 8MB
  bf16* v         = (bf16*)(ws + 0);        // 8MB (keys_ln dead)
  bf16* values_ln = (bf16*)(ws + 8 * MB);   // 8MB
  bf16* qk        = (bf16*)(ws + 16 * MB);  // 16MB
  bf16* attn      = (bf16*)(ws + 16 * MB);  // 8MB (qk dead)
  bf16* vt        = (bf16*)(ws + 24 * MB);  // 8MB
  bf16* qln       = (bf16*)(ws + 32 * MB);  // 8MB
  bf16* kln       = (bf16*)(ws + 40 * MB);  // 8MB
  bf16* wqkT      = (bf16*)(ws + 48 * MB);  // 4MB
  bf16* wvT       = (bf16*)(ws + 52 * MB);  // 2MB
  bf16* woutT     = (bf16*)(ws + 54 * MB);  // 2MB

  ln_kernel<float><<<dim3(4096), 256, 0, stream>>>(keys, 1024, qk_g, qk_b, keys_ln, 1024);
  ln_kernel<float><<<dim3(4096), 256, 0, stream>>>(values, 1024, val_g, val_b, values_ln, 1024);
  transpose_kernel<float><<<dim3(32, 16, 1), 256, 0, stream>>>(w_qk, wqkT, 1024, 2048);
  transpose_kernel<float><<<dim3(16, 16, 1), 256, 0, stream>>>(w_v, wvT, 1024, 1024);
  transpose_kernel<float><<<dim3(16, 16, 1), 256, 0, stream>>>(w_out, woutT, 1024, 1024);
  gemm_bt_kernel<bf16><<<dim3(16, 32), 256, 0, stream>>>(keys_ln, wqkT, nullptr, qk, 4096, 2048, 1024, 0);
  ln_kernel<bf16><<<dim3(4096), 256, 0, stream>>>(qk, 2048, qry_g, qry_b, qln, 1024);
  ln_kernel<bf16><<<dim3(4096), 256, 0, stream>>>(qk + 1024, 2048, key_g, key_b, kln, 1024);
  gemm_bt_kernel<bf16><<<dim3(8, 32), 256, 0, stream>>>(values_ln, wvT, nullptr, v, 4096, 1024, 1024, 0);
  transpose_kernel<bf16><<<dim3(16, 32, 2), 256, 0, stream>>>(v, vt, 2048, 1024);
  flash_kernel<<<dim3(16, 32), 256, 0, stream>>>(qln, kln, vt, attn);
  gemm_bt_kernel<float><<<dim3(8, 32), 256, 0, stream>>>(attn, woutT, b_out, out, 4096, 1024, 1024, 1);
}

// Round 5
// 272.587 us; speedup vs baseline: 1.3694x; 1.0608x over previous
//
#include <hip/hip_runtime.h>
#include <hip/hip_bf16.h>
#include <type_traits>

// SelfAttention fused block, MI355X/gfx950.
// R4b: R4 with the __builtin_bit_cast(unsigned, __hip_bfloat162) compile error
//      fixed via union type-punning. Flash: dbuf K/V prefetch with raw s_barrier
//      + manual vmcnt(4) (never drains to 0), wave-private P round-trip with
//      lgkmcnt-only sync, packed bf16 cvt. GEMM templated on BM; G2/G3 BM=64.

typedef __hip_bfloat16 bf16;
typedef __attribute__((ext_vector_type(8))) short bf16x8;
typedef __attribute__((ext_vector_type(4))) float f32x4;

#define MFMA_BF16(a, b, c) __builtin_amdgcn_mfma_f32_16x16x32_bf16((a), (b), (c), 0, 0, 0)

__device__ __forceinline__ float us2f(unsigned short u) {
  unsigned int v = ((unsigned int)u) << 16;
  return __builtin_bit_cast(float, v);
}

__device__ __forceinline__ unsigned pack_bf16x2(float a, float b) {
  union { __hip_bfloat162 h; unsigned u; } cv;
  cv.h = __float22bfloat162_rn(float2{a, b});
  return cv.u;
}

// async global->LDS, 16B per lane; lane i's dest = wave-uniform base + i*16
__device__ __forceinline__ void gl_lds16(const bf16* g, bf16* l) {
  __builtin_amdgcn_global_load_lds(
      (const __attribute__((address_space(1))) void*)g,
      (__attribute__((address_space(3))) void*)l, 16, 0, 0);
}

// ---------------- fused pair of LayerNorms: grid (rows, 2) ----------------
template <typename TIN>
__global__ __launch_bounds__(256) void ln2_kernel(
    const TIN* __restrict__ in0, const TIN* __restrict__ in1, int stride,
    const float* __restrict__ g0, const float* __restrict__ b0,
    const float* __restrict__ g1, const float* __restrict__ b1,
    bf16* __restrict__ out0, bf16* __restrict__ out1, int D)
{
  const int which = blockIdx.y;
  const TIN* in = which ? in1 : in0;
  const float* gamma = which ? g1 : g0;
  const float* beta = which ? b1 : b0;
  bf16* out = which ? out1 : out0;
  const int row = blockIdx.x;
  const int t = threadIdx.x;
  float x0, x1, x2, x3;
  if constexpr (std::is_same_v<TIN, float>) {
    float4 u = *(const float4*)(in + (size_t)row * stride + t * 4);
    x0 = u.x; x1 = u.y; x2 = u.z; x3 = u.w;
  } else {
    ushort4 u = *(const ushort4*)(in + (size_t)row * stride + t * 4);
    x0 = us2f(u.x); x1 = us2f(u.y); x2 = us2f(u.z); x3 = us2f(u.w);
  }
  float s = x0 + x1 + x2 + x3;
  float s2 = x0 * x0 + x1 * x1 + x2 * x2 + x3 * x3;
#pragma unroll
  for (int m = 1; m < 64; m <<= 1) {
    s += __shfl_xor(s, m);
    s2 += __shfl_xor(s2, m);
  }
  __shared__ float red[10];
  const int w = t >> 6, lane = t & 63;
  if (lane == 0) { red[w] = s; red[4 + w] = s2; }
  __syncthreads();
  if (t == 0) {
    float S = red[0] + red[1] + red[2] + red[3];
    float S2 = red[4] + red[5] + red[6] + red[7];
    float mu = S / (float)D;
    float var = S2 / (float)D - mu * mu;
    red[8] = mu;
    red[9] = rsqrtf(var + 1e-5f);
  }
  __syncthreads();
  const float mu = red[8], rs = red[9];
  float4 g4 = *(const float4*)(gamma + t * 4);
  float4 b4 = *(const float4*)(beta + t * 4);
  uint2 o;
  o.x = pack_bf16x2((x0 - mu) * rs * g4.x + b4.x, (x1 - mu) * rs * g4.y + b4.y);
  o.y = pack_bf16x2((x2 - mu) * rs * g4.z + b4.z, (x3 - mu) * rs * g4.w + b4.w);
  *(uint2*)(out + (size_t)row * D + t * 4) = o;
}

// ---------------- transpose: in (R,C) TIN -> out (C,R) bf16, 64x64 tiles ----------------
// pair mode: if s1 != nullptr, blockIdx.z selects (s0->d0) / (s1->d1); else z batches s0.
template <typename TIN>
__global__ __launch_bounds__(256) void transpose_kernel(
    const TIN* __restrict__ s0, bf16* __restrict__ d0,
    const TIN* __restrict__ s1, bf16* __restrict__ d1, int R, int C)
{
  __shared__ float tile[64][68];
  const TIN* in;
  bf16* out;
  size_t boff;
  if (s1 != nullptr) {
    in = blockIdx.z ? s1 : s0;
    out = blockIdx.z ? d1 : d0;
    boff = 0;
  } else {
    in = s0; out = d0;
    boff = (size_t)blockIdx.z * (size_t)R * (size_t)C;
  }
  const int r0 = blockIdx.y * 64, c0 = blockIdx.x * 64;
  const int t = threadIdx.x;
  const int lr = t >> 2, lc = (t & 3) * 16;
  if constexpr (std::is_same_v<TIN, float>) {
    const float* src = in + boff + (size_t)(r0 + lr) * C + (c0 + lc);
#pragma unroll
    for (int i = 0; i < 4; ++i) {
      float4 u = *(const float4*)(src + i * 4);
      tile[lr][lc + i * 4 + 0] = u.x;
      tile[lr][lc + i * 4 + 1] = u.y;
      tile[lr][lc + i * 4 + 2] = u.z;
      tile[lr][lc + i * 4 + 3] = u.w;
    }
  } else {
    const bf16* src = in + boff + (size_t)(r0 + lr) * C + (c0 + lc);
#pragma unroll
    for (int i = 0; i < 2; ++i) {
      ushort4 a = *(const ushort4*)(src + i * 8);
      ushort4 b = *(const ushort4*)(src + i * 8 + 4);
      tile[lr][lc + i * 8 + 0] = us2f(a.x); tile[lr][lc + i * 8 + 1] = us2f(a.y);
      tile[lr][lc + i * 8 + 2] = us2f(a.z); tile[lr][lc + i * 8 + 3] = us2f(a.w);
      tile[lr][lc + i * 8 + 4] = us2f(b.x); tile[lr][lc + i * 8 + 5] = us2f(b.y);
      tile[lr][lc + i * 8 + 6] = us2f(b.z); tile[lr][lc + i * 8 + 7] = us2f(b.w);
    }
  }
  __syncthreads();
  __align__(16) bf16 tmp[16];
#pragma unroll
  for (int j = 0; j < 16; ++j) tmp[j] = __float2bfloat16(tile[lc + j][lr]);
  bf16* dst = out + boff + (size_t)(c0 + lr) * R + (r0 + lc);
  *(bf16x8*)dst       = *(const bf16x8*)&tmp[0];
  *(bf16x8*)(dst + 8) = *(const bf16x8*)&tmp[8];
}

// ---------------- GEMM: C(M,N) = A(M,K) @ Bt(N,K)^T (+bias), bf16 in, fp32 accum ----------------
// BM in {128, 64}; BN = 128. grid = (N/128, M/BM), 256 threads, 2x2 waves.
template <int BM, typename TOUT>
__global__ __launch_bounds__(256) void gemm_bt_kernel(
    const bf16* __restrict__ A, const bf16* __restrict__ Bt,
    const float* __restrict__ bias, TOUT* __restrict__ C,
    int M, int N, int K, int has_bias)
{
  constexpr int MT = BM / 32;  // mfma row-tiles per wave
  __shared__ __align__(16) bf16 lA[BM * 32];
  __shared__ __align__(16) bf16 lB[128 * 32];
  const int t = threadIdx.x;
  const int w = t >> 6, lane = t & 63, l15 = lane & 15, quad = lane >> 4;
  const int wy = w >> 1, wx = w & 1;
  const int by = blockIdx.y, bx = blockIdx.x;
  const bf16* Ab = A + (size_t)by * BM * K;
  const bf16* Bb = Bt + (size_t)bx * 128 * K;
  f32x4 acc[MT][4] = {};

  for (int kc = 0; kc < K; kc += 32) {
    __syncthreads();
#pragma unroll
    for (int s = t; s < BM * 4; s += 256)
      gl_lds16(Ab + (size_t)(s >> 2) * K + kc + (s & 3) * 8, lA + s * 8);
#pragma unroll
    for (int s = t; s < 512; s += 256)
      gl_lds16(Bb + (size_t)(s >> 2) * K + kc + (s & 3) * 8, lB + s * 8);
    __syncthreads();
    bf16x8 af[MT], bfr[4];
#pragma unroll
    for (int mt = 0; mt < MT; ++mt)
      af[mt] = *(const bf16x8*)&lA[(wy * (BM / 2) + mt * 16 + l15) * 32 + quad * 8];
#pragma unroll
    for (int nt = 0; nt < 4; ++nt)
      bfr[nt] = *(const bf16x8*)&lB[(wx * 64 + nt * 16 + l15) * 32 + quad * 8];
#pragma unroll
    for (int mt = 0; mt < MT; ++mt)
#pragma unroll
      for (int nt = 0; nt < 4; ++nt)
        acc[mt][nt] = MFMA_BF16(af[mt], bfr[nt], acc[mt][nt]);
  }

  const int row_base = by * BM + wy * (BM / 2);
  const int col_base = bx * 128 + wx * 64;
#pragma unroll
  for (int mt = 0; mt < MT; ++mt)
#pragma unroll
    for (int nt = 0; nt < 4; ++nt) {
      const int col = col_base + nt * 16 + l15;
      const float bb = has_bias ? bias[col] : 0.0f;
#pragma unroll
      for (int r = 0; r < 4; ++r) {
        const int row = row_base + mt * 16 + quad * 4 + r;
        float v = acc[mt][nt][r] + bb;
        if constexpr (std::is_same_v<TOUT, bf16>)
          C[(size_t)row * N + col] = __float2bfloat16(v);
        else
          C[(size_t)row * N + col] = v;
      }
    }
}

// ---------------- Flash attention (R4: dbuf prefetch, raw barriers) ----------------
// Q/K: (B*N, 1024) rows, head h at cols h*64..h*64+63. Vt: per (b,h) V^T (64 d x 2048 n).
// Block: 128 q rows (4 waves x 32), loop over 32 k-tiles of 64, K/V double-buffered.
// Sync per iter: s_barrier / stage(next) / s_waitcnt vmcnt(4) / s_barrier — never vmcnt(0).
// P round-trip is wave-private (lgkmcnt(0) only, no block barrier).
__global__ __launch_bounds__(256) void flash_kernel(
    const bf16* __restrict__ Q, const bf16* __restrict__ Km,
    const bf16* __restrict__ Vt, bf16* __restrict__ O)
{
  __shared__ __align__(16) bf16 smem[9216 + 8192 + 8192 + 8192];
  bf16* lP = smem;                         // 4 waves x 32x72
  bf16* lQ = smem + 9216;                  // 128x64
  bf16* lKb = smem + 9216 + 8192;          // 2 x 64x64
  bf16* lVb = smem + 9216 + 8192 + 8192;   // 2 x 64x64
  const int t = threadIdx.x;
  const int w = t >> 6, lane = t & 63, l15 = lane & 15, quad = lane >> 4;
  const int qt = blockIdx.x, bh = blockIdx.y;
  const int b = bh >> 4, h = bh & 15;
  const int qrow0 = b * 2048 + qt * 128;
  const bf16* qbase = Q + (size_t)qrow0 * 1024 + h * 64;
  const bf16* kbase = Km + ((size_t)(b * 2048)) * 1024 + h * 64;
  const bf16* vbase = Vt + ((size_t)(b * 1024 + h * 64)) * 2048;
  bf16* lPm = lP + w * (32 * 72);

  // prologue: stage Q (4 loads/thread) + K/V tile 0 (4 loads/thread)
#pragma unroll
  for (int i = 0; i < 4; ++i) {
    int s = i * 256 + t;
    int row = s >> 3, c = (s & 7) ^ (row & 7);
    gl_lds16(qbase + (size_t)row * 1024 + (c << 3), lQ + s * 8);
  }
#pragma unroll
  for (int i = 0; i < 2; ++i) {
    int s = i * 256 + t;
    int row = s >> 3, c = (s & 7) ^ (row & 7);
    gl_lds16(kbase + (size_t)row * 1024 + (c << 3), lKb + s * 8);
    gl_lds16(vbase + (size_t)row * 2048 + (c << 3), lVb + s * 8);
  }
  asm volatile("s_waitcnt vmcnt(4)" ::: "memory");  // Q's 4 done (FIFO), tile0 in flight
  __builtin_amdgcn_s_barrier();

  const int sw = (quad ^ (l15 & 7)) << 3;
  bf16x8 qf[2][2];
#pragma unroll
  for (int mset = 0; mset < 2; ++mset) {
    const int row = w * 32 + mset * 16 + l15;
    qf[mset][0] = *(const bf16x8*)&lQ[row * 64 + sw];
    qf[mset][1] = *(const bf16x8*)&lQ[row * 64 + (sw ^ 32)];
  }

  f32x4 o_acc[4][2] = {};   // [dt][mset]: O^T row d = dt*16+quad*4+r, col m = mset*16+l15
  f32x4 l_vec[2] = {};      // in-lane partial row sums
  const float CEXP = 0.03125f * 1.44269504f;  // SCALE * log2(e)

  for (int kt = 0; kt < 32; ++kt) {
    const int cur = kt & 1;
    bf16* lK = lKb + cur * 4096;
    bf16* lV = lVb + cur * 4096;
    bf16* lKn = lKb + (cur ^ 1) * 4096;
    bf16* lVn = lVb + (cur ^ 1) * 4096;

    __builtin_amdgcn_s_barrier();  // all waves done reading buf cur^1 (prev iter)
    {
      const int ktn = (kt + 1) & 31;  // wrap: last iter restages tile 0 into dead buf
#pragma unroll
      for (int i = 0; i < 2; ++i) {
        int s = i * 256 + t;
        int row = s >> 3, c = (s & 7) ^ (row & 7);
        gl_lds16(kbase + (size_t)(ktn * 64 + row) * 1024 + (c << 3), lKn + s * 8);
        gl_lds16(vbase + (size_t)row * 2048 + ktn * 64 + (c << 3), lVn + s * 8);
      }
    }
    asm volatile("s_waitcnt vmcnt(4)" ::: "memory");  // our cur-stage done; next in flight
    __builtin_amdgcn_s_barrier();                     // everyone's cur-stage done

    bf16x8 kf[4][2], vf[4][2];
#pragma unroll
    for (int nt = 0; nt < 4; ++nt) {
      kf[nt][0] = *(const bf16x8*)&lK[(nt * 16 + l15) * 64 + sw];
      kf[nt][1] = *(const bf16x8*)&lK[(nt * 16 + l15) * 64 + (sw ^ 32)];
    }
#pragma unroll
    for (int dt = 0; dt < 4; ++dt) {
      vf[dt][0] = *(const bf16x8*)&lV[(dt * 16 + l15) * 64 + sw];
      vf[dt][1] = *(const bf16x8*)&lV[(dt * 16 + l15) * 64 + (sw ^ 32)];
    }

    // S^T + exp2 + P write (wave-private region)
#pragma unroll
    for (int mset = 0; mset < 2; ++mset) {
#pragma unroll
      for (int nt = 0; nt < 4; ++nt) {
        f32x4 z = {};
        z = MFMA_BF16(kf[nt][0], qf[mset][0], z);
        z = MFMA_BF16(kf[nt][1], qf[mset][1], z);
        f32x4 p;
#pragma unroll
        for (int r = 0; r < 4; ++r) p[r] = exp2f(z[r] * CEXP);
        l_vec[mset] += p;
        uint2 pk;
        pk.x = pack_bf16x2(p[0], p[1]);
        pk.y = pack_bf16x2(p[2], p[3]);
        *(uint2*)&lPm[(mset * 16 + l15) * 72 + nt * 16 + quad * 4] = pk;
      }
    }
    asm volatile("s_waitcnt lgkmcnt(0)" ::: "memory");  // P writes landed (wave-private)

#pragma unroll
    for (int mset = 0; mset < 2; ++mset) {
      const bf16* pr = &lPm[(mset * 16 + l15) * 72 + quad * 8];
      bf16x8 pf0 = *(const bf16x8*)pr;
      bf16x8 pf1 = *(const bf16x8*)(pr + 32);
#pragma unroll
      for (int dt = 0; dt < 4; ++dt) {
        o_acc[dt][mset] = MFMA_BF16(vf[dt][0], pf0, o_acc[dt][mset]);
        o_acc[dt][mset] = MFMA_BF16(vf[dt][1], pf1, o_acc[dt][mset]);
      }
    }
  }

  // epilogue: cross-quad row sums + divide + store O^T fragments
#pragma unroll
  for (int mset = 0; mset < 2; ++mset) {
    float tsum = l_vec[mset][0] + l_vec[mset][1] + l_vec[mset][2] + l_vec[mset][3];
    tsum += __shfl_xor(tsum, 16);
    tsum += __shfl_xor(tsum, 32);
    const float inv = 1.0f / tsum;
    const int m = qrow0 + w * 32 + mset * 16 + l15;
#pragma unroll
    for (int dt = 0; dt < 4; ++dt) {
      uint2 ok;
      ok.x = pack_bf16x2(o_acc[dt][mset][0] * inv, o_acc[dt][mset][1] * inv);
      ok.y = pack_bf16x2(o_acc[dt][mset][2] * inv, o_acc[dt][mset][3] * inv);
      *(uint2*)&O[(size_t)m * 1024 + h * 64 + dt * 16 + quad * 4] = ok;
    }
  }
}

extern "C" void kernel_launch(void* const* d_in, const int* in_sizes, int n_in,
                              void* d_out, int out_size, void* d_ws, size_t ws_size,
                              hipStream_t stream)
{
  (void)in_sizes; (void)n_in; (void)out_size; (void)ws_size;
  const float* keys   = (const float*)d_in[0];
  const float* values = (const float*)d_in[1];
  const float* qk_g   = (const float*)d_in[2];
  const float* qk_b   = (const float*)d_in[3];
  const float* val_g  = (const float*)d_in[4];
  const float* val_b  = (const float*)d_in[5];
  const float* key_g  = (const float*)d_in[6];
  const float* key_b  = (const float*)d_in[7];
  const float* qry_g  = (const float*)d_in[8];
  const float* qry_b  = (const float*)d_in[9];
  const float* w_qk   = (const float*)d_in[10];
  const float* w_v    = (const float*)d_in[11];
  const float* w_out  = (const float*)d_in[12];
  const float* b_out  = (const float*)d_in[13];
  float* out = (float*)d_out;

  char* ws = (char*)d_ws;
  const size_t MB = 1024 * 1024;
  bf16* keys_ln   = (bf16*)(ws + 0);        // 8MB
  bf16* v         = (bf16*)(ws + 0);        // 8MB (keys_ln dead)
  bf16* values_ln = (bf16*)(ws + 8 * MB);   // 8MB
  bf16* qk        = (bf16*)(ws + 16 * MB);  // 16MB
  bf16* attn      = (bf16*)(ws + 16 * MB);  // 8MB (qk dead)
  bf16* vt        = (bf16*)(ws + 24 * MB);  // 8MB
  bf16* qln       = (bf16*)(ws + 32 * MB);  // 8MB
  bf16* kln       = (bf16*)(ws + 40 * MB);  // 8MB
  bf16* wqkT      = (bf16*)(ws + 48 * MB);  // 4MB
  bf16* wvT       = (bf16*)(ws + 52 * MB);  // 2MB
  bf16* woutT     = (bf16*)(ws + 54 * MB);  // 2MB

  // L1: both input layernorms in one launch
  ln2_kernel<float><<<dim3(4096, 2), 256, 0, stream>>>(
      keys, values, 1024, qk_g, qk_b, val_g, val_b, keys_ln, values_ln, 1024);
  // L2: w_qk transpose; L3: w_v + w_out transposes (paired via z)
  transpose_kernel<float><<<dim3(32, 16, 1), 256, 0, stream>>>(w_qk, wqkT, nullptr, nullptr, 1024, 2048);
  transpose_kernel<float><<<dim3(16, 16, 2), 256, 0, stream>>>(w_v, wvT, w_out, woutT, 1024, 1024);
  // L4: qk = keys_ln @ w_qk (4096 x 2048)
  gemm_bt_kernel<128, bf16><<<dim3(16, 32), 256, 0, stream>>>(keys_ln, wqkT, nullptr, qk, 4096, 2048, 1024, 0);
  // L5: q/k layernorms in one launch (bf16 in, row stride 2048)
  ln2_kernel<bf16><<<dim3(4096, 2), 256, 0, stream>>>(
      qk, qk + 1024, 2048, qry_g, qry_b, key_g, key_b, qln, kln, 1024);
  // L6: v = values_ln @ w_v (4096 x 1024), BM=64 -> 512 blocks
  gemm_bt_kernel<64, bf16><<<dim3(8, 64), 256, 0, stream>>>(values_ln, wvT, nullptr, v, 4096, 1024, 1024, 0);
  // L7: per-batch transpose v -> vt[(b*1024 + d)*2048 + n]
  transpose_kernel<bf16><<<dim3(16, 32, 2), 256, 0, stream>>>(v, vt, nullptr, nullptr, 2048, 1024);
  // L8: flash attention -> attn
  flash_kernel<<<dim3(16, 32), 256, 0, stream>>>(qln, kln, vt, attn);
  // L9: out = attn @ w_out + b_out (fp32 out), BM=64 -> 512 blocks
  gemm_bt_kernel<64, float><<<dim3(8, 64), 256, 0, stream>>>(attn, woutT, b_out, out, 4096, 1024, 1024, 1);
}

// Round 6
// 260.711 us; speedup vs baseline: 1.4318x; 1.0455x over previous
//
#include <hip/hip_runtime.h>
#include <hip/hip_bf16.h>
#include <type_traits>

// SelfAttention fused block, MI355X/gfx950.
// R6: flash VALU diet — native v_exp_f32 (scale folded into q-LN), v_perm
//     truncating bf16 pack for P, hoisted staging addresses. GEMMs get the
//     raw-barrier dbuf (vmcnt(N), never 0). G6 writes vt directly (transposed
//     store) — v-transpose launch deleted. 8 launches.

typedef __hip_bfloat16 bf16;
typedef __attribute__((ext_vector_type(8))) short bf16x8;
typedef __attribute__((ext_vector_type(4))) float f32x4;

#define MFMA_BF16(a, b, c) __builtin_amdgcn_mfma_f32_16x16x32_bf16((a), (b), (c), 0, 0, 0)

__device__ __forceinline__ float us2f(unsigned short u) {
  unsigned int v = ((unsigned int)u) << 16;
  return __builtin_bit_cast(float, v);
}

__device__ __forceinline__ unsigned pack_bf16x2(float a, float b) {  // RNE (epilogues)
  union { __hip_bfloat162 h; unsigned u; } cv;
  cv.h = __float22bfloat162_rn(float2{a, b});
  return cv.u;
}

__device__ __forceinline__ unsigned pack_bf16x2_trunc(float a, float b) {  // 1x v_perm
  return __builtin_amdgcn_perm(__builtin_bit_cast(unsigned, b),
                               __builtin_bit_cast(unsigned, a), 0x07060302u);
}

// async global->LDS, 16B per lane; lane i's dest = wave-uniform base + i*16
__device__ __forceinline__ void gl_lds16(const bf16* g, bf16* l) {
  __builtin_amdgcn_global_load_lds(
      (const __attribute__((address_space(1))) void*)g,
      (__attribute__((address_space(3))) void*)l, 16, 0, 0);
}

// ---------------- fused pair of LayerNorms: grid (rows, 2); out scaled by sc ----------------
template <typename TIN>
__global__ __launch_bounds__(256) void ln2_kernel(
    const TIN* __restrict__ in0, const TIN* __restrict__ in1, int stride,
    const float* __restrict__ g0, const float* __restrict__ b0,
    const float* __restrict__ g1, const float* __restrict__ b1,
    bf16* __restrict__ out0, bf16* __restrict__ out1, int D,
    float sc0, float sc1)
{
  const int which = blockIdx.y;
  const TIN* in = which ? in1 : in0;
  const float* gamma = which ? g1 : g0;
  const float* beta = which ? b1 : b0;
  bf16* out = which ? out1 : out0;
  const float sc = which ? sc1 : sc0;
  const int row = blockIdx.x;
  const int t = threadIdx.x;
  float x0, x1, x2, x3;
  if constexpr (std::is_same_v<TIN, float>) {
    float4 u = *(const float4*)(in + (size_t)row * stride + t * 4);
    x0 = u.x; x1 = u.y; x2 = u.z; x3 = u.w;
  } else {
    ushort4 u = *(const ushort4*)(in + (size_t)row * stride + t * 4);
    x0 = us2f(u.x); x1 = us2f(u.y); x2 = us2f(u.z); x3 = us2f(u.w);
  }
  float s = x0 + x1 + x2 + x3;
  float s2 = x0 * x0 + x1 * x1 + x2 * x2 + x3 * x3;
#pragma unroll
  for (int m = 1; m < 64; m <<= 1) {
    s += __shfl_xor(s, m);
    s2 += __shfl_xor(s2, m);
  }
  __shared__ float red[10];
  const int w = t >> 6, lane = t & 63;
  if (lane == 0) { red[w] = s; red[4 + w] = s2; }
  __syncthreads();
  if (t == 0) {
    float S = red[0] + red[1] + red[2] + red[3];
    float S2 = red[4] + red[5] + red[6] + red[7];
    float mu = S / (float)D;
    float var = S2 / (float)D - mu * mu;
    red[8] = mu;
    red[9] = rsqrtf(var + 1e-5f);
  }
  __syncthreads();
  const float mu = red[8], rs = red[9];
  float4 g4 = *(const float4*)(gamma + t * 4);
  float4 b4 = *(const float4*)(beta + t * 4);
  uint2 o;
  o.x = pack_bf16x2(((x0 - mu) * rs * g4.x + b4.x) * sc, ((x1 - mu) * rs * g4.y + b4.y) * sc);
  o.y = pack_bf16x2(((x2 - mu) * rs * g4.z + b4.z) * sc, ((x3 - mu) * rs * g4.w + b4.w) * sc);
  *(uint2*)(out + (size_t)row * D + t * 4) = o;
}

// ---------------- transpose: in (R,C) fp32 -> out (C,R) bf16, 64x64 tiles ----------------
// pair mode: if s1 != nullptr, blockIdx.z selects (s0->d0)/(s1->d1).
__global__ __launch_bounds__(256) void transpose_kernel(
    const float* __restrict__ s0, bf16* __restrict__ d0,
    const float* __restrict__ s1, bf16* __restrict__ d1, int R, int C)
{
  __shared__ float tile[64][68];
  const float* in = (s1 && blockIdx.z) ? s1 : s0;
  bf16* out = (s1 && blockIdx.z) ? d1 : d0;
  const int r0 = blockIdx.y * 64, c0 = blockIdx.x * 64;
  const int t = threadIdx.x;
  const int lr = t >> 2, lc = (t & 3) * 16;
  const float* src = in + (size_t)(r0 + lr) * C + (c0 + lc);
#pragma unroll
  for (int i = 0; i < 4; ++i) {
    float4 u = *(const float4*)(src + i * 4);
    tile[lr][lc + i * 4 + 0] = u.x;
    tile[lr][lc + i * 4 + 1] = u.y;
    tile[lr][lc + i * 4 + 2] = u.z;
    tile[lr][lc + i * 4 + 3] = u.w;
  }
  __syncthreads();
  __align__(16) bf16 tmp[16];
#pragma unroll
  for (int j = 0; j < 16; ++j) tmp[j] = __float2bfloat16(tile[lc + j][lr]);
  bf16* dst = out + (size_t)(c0 + lr) * R + (r0 + lc);
  *(bf16x8*)dst       = *(const bf16x8*)&tmp[0];
  *(bf16x8*)(dst + 8) = *(const bf16x8*)&tmp[8];
}

// ---------------- GEMM: C(M,N) = A(M,K) @ Bt(N,K)^T (+bias), bf16 in, fp32 accum ----------------
// Double-buffered K-loop with raw s_barrier + vmcnt(L) (never drains to 0).
// TMODE 0: C[row*N+col] (TOUT bf16/float). TMODE 1: vt-transposed bf16 store
//   vt[((row>>11)*1024 + col)*2048 + (row&2047)] (b64 per lane, contiguous n).
template <int BM, int TMODE, typename TOUT>
__global__ __launch_bounds__(256) void gemm_bt_kernel(
    const bf16* __restrict__ A, const bf16* __restrict__ Bt,
    const float* __restrict__ bias, TOUT* __restrict__ C,
    int M, int N, int K, int has_bias)
{
  constexpr int MT = BM / 32;        // mfma row-tiles per wave
  constexpr int LA = (BM * 4) / 256; // A 16B-slots per thread (2 or 1)
  __shared__ __align__(16) bf16 lA[2 * BM * 32];
  __shared__ __align__(16) bf16 lB[2 * 128 * 32];
  const int t = threadIdx.x;
  const int w = t >> 6, lane = t & 63, l15 = lane & 15, quad = lane >> 4;
  const int wy = w >> 1, wx = w & 1;
  const bf16* Ab = A + (size_t)blockIdx.y * BM * K;
  const bf16* Bb = Bt + (size_t)blockIdx.x * 128 * K;
  f32x4 acc[MT][4] = {};

  // prologue: tile 0 -> buf 0
#pragma unroll
  for (int i = 0; i < LA; ++i) {
    int s = i * 256 + t;
    gl_lds16(Ab + (size_t)(s >> 2) * K + (s & 3) * 8, lA + s * 8);
  }
#pragma unroll
  for (int i = 0; i < 2; ++i) {
    int s = i * 256 + t;
    gl_lds16(Bb + (size_t)(s >> 2) * K + (s & 3) * 8, lB + s * 8);
  }

  const int niter = K >> 5;
  for (int it = 0; it < niter; ++it) {
    const int cur = it & 1;
    __builtin_amdgcn_s_barrier();  // all waves done reading buf cur^1
    {
      int nkc = (it + 1 < niter) ? (it + 1) * 32 : 0;  // wrap: restage tile0 (dead)
      bf16* dA = lA + (cur ^ 1) * BM * 32;
      bf16* dB = lB + (cur ^ 1) * 4096;
#pragma unroll
      for (int i = 0; i < LA; ++i) {
        int s = i * 256 + t;
        gl_lds16(Ab + (size_t)(s >> 2) * K + nkc + (s & 3) * 8, dA + s * 8);
      }
#pragma unroll
      for (int i = 0; i < 2; ++i) {
        int s = i * 256 + t;
        gl_lds16(Bb + (size_t)(s >> 2) * K + nkc + (s & 3) * 8, dB + s * 8);
      }
    }
    if constexpr (LA + 2 == 4) asm volatile("s_waitcnt vmcnt(4)" ::: "memory");
    else                       asm volatile("s_waitcnt vmcnt(3)" ::: "memory");
    __builtin_amdgcn_s_barrier();  // everyone's cur-tile staged

    const bf16* sA = lA + cur * BM * 32;
    const bf16* sB = lB + cur * 4096;
    bf16x8 af[MT], bfr[4];
#pragma unroll
    for (int mt = 0; mt < MT; ++mt)
      af[mt] = *(const bf16x8*)&sA[(wy * (BM / 2) + mt * 16 + l15) * 32 + quad * 8];
#pragma unroll
    for (int nt = 0; nt < 4; ++nt)
      bfr[nt] = *(const bf16x8*)&sB[(wx * 64 + nt * 16 + l15) * 32 + quad * 8];
#pragma unroll
    for (int mt = 0; mt < MT; ++mt)
#pragma unroll
      for (int nt = 0; nt < 4; ++nt)
        acc[mt][nt] = MFMA_BF16(af[mt], bfr[nt], acc[mt][nt]);
  }

  const int row_base = blockIdx.y * BM + wy * (BM / 2);
  const int col_base = blockIdx.x * 128 + wx * 64;
#pragma unroll
  for (int mt = 0; mt < MT; ++mt)
#pragma unroll
    for (int nt = 0; nt < 4; ++nt) {
      const int col = col_base + nt * 16 + l15;
      if constexpr (TMODE == 1) {
        const int row0 = row_base + mt * 16 + quad * 4;
        const int b = row0 >> 11, n0 = row0 & 2047;
        uint2 ok;
        ok.x = pack_bf16x2(acc[mt][nt][0], acc[mt][nt][1]);
        ok.y = pack_bf16x2(acc[mt][nt][2], acc[mt][nt][3]);
        *(uint2*)&((bf16*)C)[((size_t)(b << 10) + col) * 2048 + n0] = ok;
      } else {
        const float bb = has_bias ? bias[col] : 0.0f;
#pragma unroll
        for (int r = 0; r < 4; ++r) {
          const int row = row_base + mt * 16 + quad * 4 + r;
          float v = acc[mt][nt][r] + bb;
          if constexpr (std::is_same_v<TOUT, bf16>)
            C[(size_t)row * N + col] = __float2bfloat16(v);
          else
            C[(size_t)row * N + col] = v;
        }
      }
    }
}

// ---------------- Flash attention (R6) ----------------
// qln is pre-scaled by SCALE*log2(e) -> S^T MFMA yields log2-domain logits;
// p = v_exp_f32 directly. P packed via v_perm truncation. dbuf K/V with raw
// s_barrier + vmcnt(4). P round-trip wave-private (lgkmcnt(0) only).
__global__ __launch_bounds__(256) void flash_kernel(
    const bf16* __restrict__ Q, const bf16* __restrict__ Km,
    const bf16* __restrict__ Vt, bf16* __restrict__ O)
{
  __shared__ __align__(16) bf16 smem[9216 + 8192 + 8192 + 8192];
  bf16* lP = smem;                         // 4 waves x 32x72
  bf16* lQ = smem + 9216;                  // 128x64
  bf16* lKb = smem + 9216 + 8192;          // 2 x 64x64
  bf16* lVb = smem + 9216 + 8192 + 8192;   // 2 x 64x64
  const int t = threadIdx.x;
  const int w = t >> 6, lane = t & 63, l15 = lane & 15, quad = lane >> 4;
  const int qt = blockIdx.x, bh = blockIdx.y;
  const int b = bh >> 4, h = bh & 15;
  const int qrow0 = b * 2048 + qt * 128;
  const bf16* qbase = Q + (size_t)qrow0 * 1024 + h * 64;
  const bf16* kbase = Km + ((size_t)(b * 2048)) * 1024 + h * 64;
  const bf16* vbase = Vt + ((size_t)(b * 1024 + h * 64)) * 2048;
  bf16* lPm = lP + w * (32 * 72);

  // thread-constant staging coords (2 slots/thread for each of K and V)
  const int sr0 = t >> 3, sc0 = ((t & 7) ^ (sr0 & 7)) << 3;
  const int sr1 = (256 + t) >> 3, sc1 = (((256 + t) & 7) ^ (sr1 & 7)) << 3;
  const bf16* kp0 = kbase + sr0 * 1024 + sc0;
  const bf16* kp1 = kbase + sr1 * 1024 + sc1;
  const bf16* vp0 = vbase + sr0 * 2048 + sc0;
  const bf16* vp1 = vbase + sr1 * 2048 + sc1;

  // prologue: stage Q (4) + K/V tile 0 (4)
#pragma unroll
  for (int i = 0; i < 4; ++i) {
    int s = i * 256 + t;
    int row = s >> 3, c = (s & 7) ^ (row & 7);
    gl_lds16(qbase + (size_t)row * 1024 + (c << 3), lQ + s * 8);
  }
  gl_lds16(kp0, lKb + t * 8);
  gl_lds16(kp1, lKb + (256 + t) * 8);
  gl_lds16(vp0, lVb + t * 8);
  gl_lds16(vp1, lVb + (256 + t) * 8);
  asm volatile("s_waitcnt vmcnt(4)" ::: "memory");  // Q done (FIFO), tile0 in flight
  __builtin_amdgcn_s_barrier();

  const int sw = (quad ^ (l15 & 7)) << 3;
  bf16x8 qf[2][2];
#pragma unroll
  for (int mset = 0; mset < 2; ++mset) {
    const int row = w * 32 + mset * 16 + l15;
    qf[mset][0] = *(const bf16x8*)&lQ[row * 64 + sw];
    qf[mset][1] = *(const bf16x8*)&lQ[row * 64 + (sw ^ 32)];
  }

  f32x4 o_acc[4][2] = {};   // [dt][mset]: O^T row d = dt*16+quad*4+r, col m = mset*16+l15
  f32x4 l_vec[2] = {};      // in-lane partial row sums

  for (int kt = 0; kt < 32; ++kt) {
    const int cur = kt & 1;
    bf16* lK = lKb + cur * 4096;
    bf16* lV = lVb + cur * 4096;
    bf16* lKn = lKb + (cur ^ 1) * 4096;
    bf16* lVn = lVb + (cur ^ 1) * 4096;

    __builtin_amdgcn_s_barrier();  // all waves done reading buf cur^1
    {
      const int ktn = (kt + 1) & 31;  // wrap: restage tile 0 into dead buf
      const int ko = ktn << 16;       // ktn*64 rows * 1024
      const int vo = ktn << 6;        // ktn*64 cols
      gl_lds16(kp0 + ko, lKn + t * 8);
      gl_lds16(kp1 + ko, lKn + (256 + t) * 8);
      gl_lds16(vp0 + vo, lVn + t * 8);
      gl_lds16(vp1 + vo, lVn + (256 + t) * 8);
    }
    asm volatile("s_waitcnt vmcnt(4)" ::: "memory");
    __builtin_amdgcn_s_barrier();

    bf16x8 kf[4][2];
#pragma unroll
    for (int nt = 0; nt < 4; ++nt) {
      kf[nt][0] = *(const bf16x8*)&lK[(nt * 16 + l15) * 64 + sw];
      kf[nt][1] = *(const bf16x8*)&lK[(nt * 16 + l15) * 64 + (sw ^ 32)];
    }

    // S^T (log2-domain) + v_exp + truncating pack + P write (wave-private)
#pragma unroll
    for (int mset = 0; mset < 2; ++mset) {
#pragma unroll
      for (int nt = 0; nt < 4; ++nt) {
        f32x4 z = {};
        z = MFMA_BF16(kf[nt][0], qf[mset][0], z);
        z = MFMA_BF16(kf[nt][1], qf[mset][1], z);
        f32x4 p;
#pragma unroll
        for (int r = 0; r < 4; ++r) p[r] = __builtin_amdgcn_exp2f(z[r]);
        l_vec[mset] += p;
        uint2 pk;
        pk.x = pack_bf16x2_trunc(p[0], p[1]);
        pk.y = pack_bf16x2_trunc(p[2], p[3]);
        *(uint2*)&lPm[(mset * 16 + l15) * 72 + nt * 16 + quad * 4] = pk;
      }
    }

    bf16x8 vf[4][2];
#pragma unroll
    for (int dt = 0; dt < 4; ++dt) {
      vf[dt][0] = *(const bf16x8*)&lV[(dt * 16 + l15) * 64 + sw];
      vf[dt][1] = *(const bf16x8*)&lV[(dt * 16 + l15) * 64 + (sw ^ 32)];
    }
    asm volatile("s_waitcnt lgkmcnt(0)" ::: "memory");  // P writes landed

#pragma unroll
    for (int mset = 0; mset < 2; ++mset) {
      const bf16* pr = &lPm[(mset * 16 + l15) * 72 + quad * 8];
      bf16x8 pf0 = *(const bf16x8*)pr;
      bf16x8 pf1 = *(const bf16x8*)(pr + 32);
#pragma unroll
      for (int dt = 0; dt < 4; ++dt) {
        o_acc[dt][mset] = MFMA_BF16(vf[dt][0], pf0, o_acc[dt][mset]);
        o_acc[dt][mset] = MFMA_BF16(vf[dt][1], pf1, o_acc[dt][mset]);
      }
    }
  }

  // epilogue: cross-quad row sums + divide + store O^T fragments
#pragma unroll
  for (int mset = 0; mset < 2; ++mset) {
    float tsum = l_vec[mset][0] + l_vec[mset][1] + l_vec[mset][2] + l_vec[mset][3];
    tsum += __shfl_xor(tsum, 16);
    tsum += __shfl_xor(tsum, 32);
    const float inv = 1.0f / tsum;
    const int m = qrow0 + w * 32 + mset * 16 + l15;
#pragma unroll
    for (int dt = 0; dt < 4; ++dt) {
      uint2 ok;
      ok.x = pack_bf16x2(o_acc[dt][mset][0] * inv, o_acc[dt][mset][1] * inv);
      ok.y = pack_bf16x2(o_acc[dt][mset][2] * inv, o_acc[dt][mset][3] * inv);
      *(uint2*)&O[(size_t)m * 1024 + h * 64 + dt * 16 + quad * 4] = ok;
    }
  }
}

extern "C" void kernel_launch(void* const* d_in, const int* in_sizes, int n_in,
                              void* d_out, int out_size, void* d_ws, size_t ws_size,
                              hipStream_t stream)
{
  (void)in_sizes; (void)n_in; (void)out_size; (void)ws_size;
  const float* keys   = (const float*)d_in[0];
  const float* values = (const float*)d_in[1];
  const float* qk_g   = (const float*)d_in[2];
  const float* qk_b   = (const float*)d_in[3];
  const float* val_g  = (const float*)d_in[4];
  const float* val_b  = (const float*)d_in[5];
  const float* key_g  = (const float*)d_in[6];
  const float* key_b  = (const float*)d_in[7];
  const float* qry_g  = (const float*)d_in[8];
  const float* qry_b  = (const float*)d_in[9];
  const float* w_qk   = (const float*)d_in[10];
  const float* w_v    = (const float*)d_in[11];
  const float* w_out  = (const float*)d_in[12];
  const float* b_out  = (const float*)d_in[13];
  float* out = (float*)d_out;

  const float CEXP = 0.03125f * 1.44269504f;  // ID^-0.5 * log2(e), folded into q-LN

  char* ws = (char*)d_ws;
  const size_t MB = 1024 * 1024;
  bf16* keys_ln   = (bf16*)(ws + 0);        // 8MB
  bf16* values_ln = (bf16*)(ws + 8 * MB);   // 8MB
  bf16* qk        = (bf16*)(ws + 16 * MB);  // 16MB
  bf16* attn      = (bf16*)(ws + 16 * MB);  // 8MB (qk dead)
  bf16* vt        = (bf16*)(ws + 24 * MB);  // 8MB
  bf16* qln       = (bf16*)(ws + 32 * MB);  // 8MB
  bf16* kln       = (bf16*)(ws + 40 * MB);  // 8MB
  bf16* wqkT      = (bf16*)(ws + 48 * MB);  // 4MB
  bf16* wvT       = (bf16*)(ws + 52 * MB);  // 2MB
  bf16* woutT     = (bf16*)(ws + 54 * MB);  // 2MB

  // L1: both input layernorms
  ln2_kernel<float><<<dim3(4096, 2), 256, 0, stream>>>(
      keys, values, 1024, qk_g, qk_b, val_g, val_b, keys_ln, values_ln, 1024, 1.0f, 1.0f);
  // L2/L3: weight transposes
  transpose_kernel<<<dim3(32, 16, 1), 256, 0, stream>>>(w_qk, wqkT, nullptr, nullptr, 1024, 2048);
  transpose_kernel<<<dim3(16, 16, 2), 256, 0, stream>>>(w_v, wvT, w_out, woutT, 1024, 1024);
  // L4: qk = keys_ln @ w_qk (4096 x 2048), dbuf
  gemm_bt_kernel<128, 0, bf16><<<dim3(16, 32), 256, 0, stream>>>(keys_ln, wqkT, nullptr, qk, 4096, 2048, 1024, 0);
  // L5: q/k layernorms; qln pre-scaled by CEXP for flash
  ln2_kernel<bf16><<<dim3(4096, 2), 256, 0, stream>>>(
      qk, qk + 1024, 2048, qry_g, qry_b, key_g, key_b, qln, kln, 1024, CEXP, 1.0f);
  // L6: v = values_ln @ w_v, stored TRANSPOSED directly into vt
  gemm_bt_kernel<64, 1, bf16><<<dim3(8, 64), 256, 0, stream>>>(values_ln, wvT, nullptr, vt, 4096, 1024, 1024, 0);
  // L7: flash attention -> attn
  flash_kernel<<<dim3(16, 32), 256, 0, stream>>>(qln, kln, vt, attn);
  // L8: out = attn @ w_out + b_out (fp32 out)
  gemm_bt_kernel<64, 0, float><<<dim3(8, 64), 256, 0, stream>>>(attn, woutT, b_out, out, 4096, 1024, 1024, 1);
}